// Round 3
// baseline (453.680 us; speedup 1.0000x reference)
//
#include <hip/hip_runtime.h>
#include <hip/hip_bf16.h>
#include <math.h>

typedef __bf16 bf16;
typedef __attribute__((ext_vector_type(8))) __bf16 bf16x8;
typedef __attribute__((ext_vector_type(4))) __bf16 bf16x4;
typedef __attribute__((ext_vector_type(4))) float f32x4;

#define EPSBN 1e-5f
#define NSLOT 128

// ---------------- K0: zero stat partials; block 0 builds dense normalized adjacency ----------------
// Ahat[d][s] = sum over edges (s->d) of dinv[s]*dinv[d], incl. self loops. Duplicate edges add.
__global__ __launch_bounds__(256) void k0_prep(const int* __restrict__ edge,
    float* __restrict__ partials,          // NSLOT*64*2 * 2 layers contiguous
    float* __restrict__ ahat)              // [64][64] fp32
{
    int tid = threadIdx.x;
    for (int i = blockIdx.x * 256 + tid; i < NSLOT * 64 * 4; i += gridDim.x * 256)
        partials[i] = 0.f;
    if (blockIdx.x != 0) return;

    __shared__ float Ah[64 * 64];
    __shared__ int deg[64];
    __shared__ float dinv[64];
    for (int i = tid; i < 4096; i += 256) Ah[i] = 0.f;
    if (tid < 64) deg[tid] = 1;                       // self loop
    __syncthreads();
    for (int e = tid; e < 512; e += 256) atomicAdd(&deg[edge[512 + e]], 1);
    __syncthreads();
    if (tid < 64) dinv[tid] = rsqrtf((float)deg[tid]);
    __syncthreads();
    for (int e = tid; e < 512; e += 256) {
        int s = edge[e], d = edge[512 + e];
        atomicAdd(&Ah[d * 64 + s], dinv[s] * dinv[d]);
    }
    if (tid < 64) atomicAdd(&Ah[tid * 64 + tid], dinv[tid] * dinv[tid]);
    __syncthreads();
    for (int i = tid; i < 4096; i += 256) ahat[i] = Ah[i];
}

// ---------------- K1: GCN layer 1, one wave per sample, all-MFMA ----------------
// MFMA1: hT[o][n] = sum_f W1[o][f] X[n][f]   (A=W1 rows, B=X rows)
// MFMA2: out[n][c] = sum_s Ahat[n][s] hT[c][s] (A=Ahat rows, B=hT rows)
__global__ __launch_bounds__(64) void k1_gcn1(
    const float* __restrict__ x,          // [B][64][67]
    const float* __restrict__ W1,         // [64][67]
    const float* __restrict__ b1,         // [64]
    const float* __restrict__ ahat,       // [64][64]
    bf16* __restrict__ g1out,             // [B][64][64]
    float* __restrict__ part1)            // [NSLOT][64][2]
{
    __shared__ bf16 hT[64 * 72];          // pitch 72 (144B, 16B-aligned rows)
    int lane = threadIdx.x;
    int q = lane >> 4, r15 = lane & 15;
    int b = blockIdx.x;

    // A-frags: W1 rows o = mt*16+r15, K padded 67->96 (predicated scalar loads: rows are 4B-aligned only)
    bf16x8 aw[4][3];
#pragma unroll
    for (int mt = 0; mt < 4; ++mt) {
        const float* wr = W1 + (mt * 16 + r15) * 67;
#pragma unroll
        for (int kt = 0; kt < 3; ++kt)
#pragma unroll
            for (int j = 0; j < 8; ++j) {
                int f = kt * 32 + q * 8 + j;
                float v = 0.f;
                if (f < 67) v = wr[f];
                aw[mt][kt][j] = (bf16)v;
            }
    }
    // B-frags: X rows n = nt*16+r15
    const float* xb = x + (size_t)b * 4288;
    bf16x8 xf[4][3];
#pragma unroll
    for (int nt = 0; nt < 4; ++nt) {
        const float* xr = xb + (nt * 16 + r15) * 67;
#pragma unroll
        for (int kt = 0; kt < 3; ++kt)
#pragma unroll
            for (int j = 0; j < 8; ++j) {
                int f = kt * 32 + q * 8 + j;
                float v = 0.f;
                if (f < 67) v = xr[f];
                xf[nt][kt][j] = (bf16)v;
            }
    }

    f32x4 z4 = {0.f, 0.f, 0.f, 0.f};
    f32x4 acc[4][4];
#pragma unroll
    for (int mt = 0; mt < 4; ++mt)
#pragma unroll
        for (int nt = 0; nt < 4; ++nt) acc[mt][nt] = z4;
#pragma unroll
    for (int kt = 0; kt < 3; ++kt)
#pragma unroll
        for (int mt = 0; mt < 4; ++mt)
#pragma unroll
            for (int nt = 0; nt < 4; ++nt)
                acc[mt][nt] = __builtin_amdgcn_mfma_f32_16x16x32_bf16(aw[mt][kt], xf[nt][kt], acc[mt][nt], 0, 0, 0);

    // write hT: element [o = mt*16+q*4+r][n = nt*16+r15]
#pragma unroll
    for (int mt = 0; mt < 4; ++mt)
#pragma unroll
        for (int nt = 0; nt < 4; ++nt)
#pragma unroll
            for (int r = 0; r < 4; ++r)
                hT[(mt * 16 + q * 4 + r) * 72 + nt * 16 + r15] = (bf16)acc[mt][nt][r];

    // A-frags: Ahat rows n = mt*16+r15 (16B-aligned: vector loads)
    bf16x8 ah[4][2];
#pragma unroll
    for (int mt = 0; mt < 4; ++mt)
#pragma unroll
        for (int kt = 0; kt < 2; ++kt) {
            const float* ar = ahat + (mt * 16 + r15) * 64 + kt * 32 + q * 8;
            f32x4 u = *(const f32x4*)ar;
            f32x4 v = *(const f32x4*)(ar + 4);
            ah[mt][kt][0] = (bf16)u[0]; ah[mt][kt][1] = (bf16)u[1];
            ah[mt][kt][2] = (bf16)u[2]; ah[mt][kt][3] = (bf16)u[3];
            ah[mt][kt][4] = (bf16)v[0]; ah[mt][kt][5] = (bf16)v[1];
            ah[mt][kt][6] = (bf16)v[2]; ah[mt][kt][7] = (bf16)v[3];
        }
    __syncthreads();                                  // drain LDS writes (single wave: cheap)

    // B-frags: hT rows c = ct*16+r15
    bf16x8 hb[4][2];
#pragma unroll
    for (int ct = 0; ct < 4; ++ct)
#pragma unroll
        for (int kt = 0; kt < 2; ++kt)
            hb[ct][kt] = *(const bf16x8*)&hT[(ct * 16 + r15) * 72 + kt * 32 + q * 8];

    f32x4 o2[4][4];
#pragma unroll
    for (int mt = 0; mt < 4; ++mt)
#pragma unroll
        for (int ct = 0; ct < 4; ++ct) o2[mt][ct] = z4;
#pragma unroll
    for (int kt = 0; kt < 2; ++kt)
#pragma unroll
        for (int mt = 0; mt < 4; ++mt)
#pragma unroll
            for (int ct = 0; ct < 4; ++ct)
                o2[mt][ct] = __builtin_amdgcn_mfma_f32_16x16x32_bf16(ah[mt][kt], hb[ct][kt], o2[mt][ct], 0, 0, 0);

    float bv[4];
#pragma unroll
    for (int ct = 0; ct < 4; ++ct) bv[ct] = b1[ct * 16 + r15];

    bf16* gp = g1out + (size_t)b * 4096;
    int slot = b & (NSLOT - 1);
#pragma unroll
    for (int mt = 0; mt < 4; ++mt)
#pragma unroll
        for (int r = 0; r < 4; ++r) {
            int n = mt * 16 + q * 4 + r;
            float s1 = 0.f, s2 = 0.f;
#pragma unroll
            for (int ct = 0; ct < 4; ++ct) {
                float v = o2[mt][ct][r] + bv[ct];
                s1 += v; s2 += v * v;
                gp[n * 64 + ct * 16 + r15] = (bf16)v;
            }
            s1 += __shfl_xor(s1, 1); s1 += __shfl_xor(s1, 2);
            s2 += __shfl_xor(s2, 1); s2 += __shfl_xor(s2, 2);
            if ((r15 & 3) == 0) {                     // 4 partial-sum lanes per row; atomics complete it
                atomicAdd(&part1[(slot * 64 + n) * 2 + 0], s1);
                atomicAdd(&part1[(slot * 64 + n) * 2 + 1], s2);
            }
        }
}

// ---------------- BN stats reduce: partials -> scale/shift per node ----------------
__global__ __launch_bounds__(64) void k_bnstats(
    const float* __restrict__ part,       // [NSLOT][64][2]
    const float* __restrict__ gamma, const float* __restrict__ beta,
    float* __restrict__ scale, float* __restrict__ shift, float inv_count)
{
    int n = blockIdx.x, t = threadIdx.x;
    float s1 = part[(t * 64 + n) * 2] + part[((t + 64) * 64 + n) * 2];
    float s2 = part[(t * 64 + n) * 2 + 1] + part[((t + 64) * 64 + n) * 2 + 1];
#pragma unroll
    for (int o = 32; o > 0; o >>= 1) { s1 += __shfl_down(s1, o); s2 += __shfl_down(s2, o); }
    if (t == 0) {
        float mean = s1 * inv_count;
        float var = s2 * inv_count - mean * mean;
        float sc = gamma[n] * rsqrtf(var + EPSBN);
        scale[n] = sc;
        shift[n] = beta[n] - mean * sc;
    }
}

// ---------------- K3: BN1+relu -> GCN layer 2, one wave per sample, all-MFMA ----------------
__global__ __launch_bounds__(64) void k3_gcn2(
    const bf16* __restrict__ g1out,       // [B][64][64]
    const float* __restrict__ W2,         // [32][64]
    const float* __restrict__ b2,
    const float* __restrict__ scale1, const float* __restrict__ shift1,
    const float* __restrict__ ahat,
    bf16* __restrict__ g2out,             // [B][64][32]
    float* __restrict__ part2)
{
    __shared__ bf16 hT[32 * 72];
    int lane = threadIdx.x;
    int q = lane >> 4, r15 = lane & 15;
    int b = blockIdx.x;

    // A-frags: W2 rows o = mt*16+r15 (rows 256B-aligned: vector loads)
    bf16x8 aw[2][2];
#pragma unroll
    for (int mt = 0; mt < 2; ++mt)
#pragma unroll
        for (int kt = 0; kt < 2; ++kt) {
            const float* wr = W2 + (mt * 16 + r15) * 64 + kt * 32 + q * 8;
            f32x4 u = *(const f32x4*)wr;
            f32x4 v = *(const f32x4*)(wr + 4);
            aw[mt][kt][0] = (bf16)u[0]; aw[mt][kt][1] = (bf16)u[1];
            aw[mt][kt][2] = (bf16)u[2]; aw[mt][kt][3] = (bf16)u[3];
            aw[mt][kt][4] = (bf16)v[0]; aw[mt][kt][5] = (bf16)v[1];
            aw[mt][kt][6] = (bf16)v[2]; aw[mt][kt][7] = (bf16)v[3];
        }

    // B-frags: y rows n = nt*16+r15, y = relu(scale1[n]*g1 + shift1[n])
    const bf16* gb = g1out + (size_t)b * 4096;
    bf16x8 yf[4][2];
#pragma unroll
    for (int nt = 0; nt < 4; ++nt) {
        int n = nt * 16 + r15;
        float ss = scale1[n], sh = shift1[n];
#pragma unroll
        for (int kt = 0; kt < 2; ++kt) {
            bf16x8 gv = *(const bf16x8*)(gb + n * 64 + kt * 32 + q * 8);
#pragma unroll
            for (int j = 0; j < 8; ++j) {
                float v = fmaxf(fmaf(ss, (float)gv[j], sh), 0.f);
                yf[nt][kt][j] = (bf16)v;
            }
        }
    }

    f32x4 z4 = {0.f, 0.f, 0.f, 0.f};
    f32x4 acc[2][4];
#pragma unroll
    for (int mt = 0; mt < 2; ++mt)
#pragma unroll
        for (int nt = 0; nt < 4; ++nt) acc[mt][nt] = z4;
#pragma unroll
    for (int kt = 0; kt < 2; ++kt)
#pragma unroll
        for (int mt = 0; mt < 2; ++mt)
#pragma unroll
            for (int nt = 0; nt < 4; ++nt)
                acc[mt][nt] = __builtin_amdgcn_mfma_f32_16x16x32_bf16(aw[mt][kt], yf[nt][kt], acc[mt][nt], 0, 0, 0);

#pragma unroll
    for (int mt = 0; mt < 2; ++mt)
#pragma unroll
        for (int nt = 0; nt < 4; ++nt)
#pragma unroll
            for (int r = 0; r < 4; ++r)
                hT[(mt * 16 + q * 4 + r) * 72 + nt * 16 + r15] = (bf16)acc[mt][nt][r];

    bf16x8 ah[4][2];
#pragma unroll
    for (int mt = 0; mt < 4; ++mt)
#pragma unroll
        for (int kt = 0; kt < 2; ++kt) {
            const float* ar = ahat + (mt * 16 + r15) * 64 + kt * 32 + q * 8;
            f32x4 u = *(const f32x4*)ar;
            f32x4 v = *(const f32x4*)(ar + 4);
            ah[mt][kt][0] = (bf16)u[0]; ah[mt][kt][1] = (bf16)u[1];
            ah[mt][kt][2] = (bf16)u[2]; ah[mt][kt][3] = (bf16)u[3];
            ah[mt][kt][4] = (bf16)v[0]; ah[mt][kt][5] = (bf16)v[1];
            ah[mt][kt][6] = (bf16)v[2]; ah[mt][kt][7] = (bf16)v[3];
        }
    __syncthreads();

    bf16x8 hb[2][2];
#pragma unroll
    for (int ct = 0; ct < 2; ++ct)
#pragma unroll
        for (int kt = 0; kt < 2; ++kt)
            hb[ct][kt] = *(const bf16x8*)&hT[(ct * 16 + r15) * 72 + kt * 32 + q * 8];

    f32x4 o2[4][2];
#pragma unroll
    for (int mt = 0; mt < 4; ++mt)
#pragma unroll
        for (int ct = 0; ct < 2; ++ct) o2[mt][ct] = z4;
#pragma unroll
    for (int kt = 0; kt < 2; ++kt)
#pragma unroll
        for (int mt = 0; mt < 4; ++mt)
#pragma unroll
            for (int ct = 0; ct < 2; ++ct)
                o2[mt][ct] = __builtin_amdgcn_mfma_f32_16x16x32_bf16(ah[mt][kt], hb[ct][kt], o2[mt][ct], 0, 0, 0);

    float bv[2];
#pragma unroll
    for (int ct = 0; ct < 2; ++ct) bv[ct] = b2[ct * 16 + r15];

    bf16* gp = g2out + (size_t)b * 2048;
    int slot = b & (NSLOT - 1);
#pragma unroll
    for (int mt = 0; mt < 4; ++mt)
#pragma unroll
        for (int r = 0; r < 4; ++r) {
            int n = mt * 16 + q * 4 + r;
            float s1 = 0.f, s2 = 0.f;
#pragma unroll
            for (int ct = 0; ct < 2; ++ct) {
                float v = o2[mt][ct][r] + bv[ct];
                s1 += v; s2 += v * v;
                gp[n * 32 + ct * 16 + r15] = (bf16)v;
            }
            s1 += __shfl_xor(s1, 1); s1 += __shfl_xor(s1, 2);
            s2 += __shfl_xor(s2, 1); s2 += __shfl_xor(s2, 2);
            if ((r15 & 3) == 0) {
                atomicAdd(&part2[(slot * 64 + n) * 2 + 0], s1);
                atomicAdd(&part2[(slot * 64 + n) * 2 + 1], s2);
            }
        }
}

// ---------------- K6: MLP1 split-K GEMM, register-prefetch pipeline ----------------
__global__ __launch_bounds__(256) void k6_mlp1(
    const float* __restrict__ A,          // [4096][2048]
    const float* __restrict__ Bw,         // [400][2048]
    float* __restrict__ part)             // [4][4096][400]
{
    __shared__ bf16 As[64 * 36];
    __shared__ bf16 Bs[64 * 36];
    int tid = threadIdx.x;
    int m0 = blockIdx.x * 64, n0 = blockIdx.y * 64, ks = blockIdx.z;
    int row = tid >> 2, seg = tid & 3;
    int w = tid >> 6, lane = tid & 63, q = lane >> 4, r15 = lane & 15;
    f32x4 z4 = {0.f, 0.f, 0.f, 0.f};
    f32x4 acc[4] = {z4, z4, z4, z4};
    const float* pA = A + (size_t)(m0 + row) * 2048 + ks * 512 + seg * 8;
    bool bvalid = (n0 + row) < 400;
    const float* pB = Bw + (size_t)(n0 + row) * 2048 + ks * 512 + seg * 8;

    f32x4 a0 = *(const f32x4*)pA;
    f32x4 a1 = *(const f32x4*)(pA + 4);
    f32x4 c0 = z4, c1 = z4;
    if (bvalid) { c0 = *(const f32x4*)pB; c1 = *(const f32x4*)(pB + 4); }

    for (int kt = 0; kt < 16; ++kt) {
        bf16x8 apk, bpk;
        apk[0] = (bf16)a0[0]; apk[1] = (bf16)a0[1]; apk[2] = (bf16)a0[2]; apk[3] = (bf16)a0[3];
        apk[4] = (bf16)a1[0]; apk[5] = (bf16)a1[1]; apk[6] = (bf16)a1[2]; apk[7] = (bf16)a1[3];
        bpk[0] = (bf16)c0[0]; bpk[1] = (bf16)c0[1]; bpk[2] = (bf16)c0[2]; bpk[3] = (bf16)c0[3];
        bpk[4] = (bf16)c1[0]; bpk[5] = (bf16)c1[1]; bpk[6] = (bf16)c1[2]; bpk[7] = (bf16)c1[3];
        __syncthreads();
        *(bf16x8*)&As[row * 36 + seg * 8] = apk;
        *(bf16x8*)&Bs[row * 36 + seg * 8] = bpk;
        __syncthreads();
        if (kt < 15) {
            pA += 32; pB += 32;
            a0 = *(const f32x4*)pA; a1 = *(const f32x4*)(pA + 4);
            if (bvalid) { c0 = *(const f32x4*)pB; c1 = *(const f32x4*)(pB + 4); }
        }
        bf16x8 a = *(const bf16x8*)&As[(w * 16 + r15) * 36 + q * 8];
#pragma unroll
        for (int nt = 0; nt < 4; ++nt) {
            bf16x8 bb = *(const bf16x8*)&Bs[(nt * 16 + r15) * 36 + q * 8];
            acc[nt] = __builtin_amdgcn_mfma_f32_16x16x32_bf16(a, bb, acc[nt], 0, 0, 0);
        }
    }
    float* pp = part + (size_t)ks * 1638400;
#pragma unroll
    for (int nt = 0; nt < 4; ++nt)
#pragma unroll
        for (int r = 0; r < 4; ++r) {
            int mm = m0 + w * 16 + q * 4 + r;
            int nn = n0 + nt * 16 + r15;
            if (nn < 400) pp[(size_t)mm * 400 + nn] = acc[nt][r];
        }
}

// ---------------- K6R: reduce 4 k-splits + bias + relu -> bf16 h1 ----------------
__global__ __launch_bounds__(256) void k6_reduce(
    const float* __restrict__ part,
    const float* __restrict__ bias,
    bf16* __restrict__ h1)
{
    int i = blockIdx.x * 256 + threadIdx.x;
    const f32x4* p = (const f32x4*)part;
    f32x4 s0 = p[i], s1v = p[i + 409600], s2v = p[i + 819200], s3v = p[i + 1228800];
    int nn = (i * 4) % 400;
    f32x4 bv = *(const f32x4*)&bias[nn];
    bf16x4 ov;
    ov[0] = (bf16)fmaxf(s0[0] + s1v[0] + s2v[0] + s3v[0] + bv[0], 0.f);
    ov[1] = (bf16)fmaxf(s0[1] + s1v[1] + s2v[1] + s3v[1] + bv[1], 0.f);
    ov[2] = (bf16)fmaxf(s0[2] + s1v[2] + s2v[2] + s3v[2] + bv[2], 0.f);
    ov[3] = (bf16)fmaxf(s0[3] + s1v[3] + s2v[3] + s3v[3] + bv[3], 0.f);
    *(bf16x4*)&h1[i * 4] = ov;
}

// ---------------- K7: MLP2  h2 = relu(h1 @ Wl2^T + bl2) ----------------
__global__ __launch_bounds__(256) void k7_mlp2(
    const bf16* __restrict__ A,           // [4096][400] bf16
    const float* __restrict__ Bw,         // [64][400] f32
    const float* __restrict__ bias,
    float* __restrict__ Cout)             // [4096][64]
{
    __shared__ bf16 As[16 * 416];
    int tid = threadIdx.x;
    int m0 = blockIdx.x * 16;
    for (int i = tid; i < 16 * 50; i += 256) {
        int rr = i / 50, cc = (i % 50) * 8;
        *(bf16x8*)&As[rr * 416 + cc] = *(const bf16x8*)(A + (size_t)(m0 + rr) * 400 + cc);
    }
    if (tid < 32) {
        int rr = tid >> 1, cc = 400 + (tid & 1) * 8;
        bf16x8 z;
#pragma unroll
        for (int k = 0; k < 8; ++k) z[k] = (bf16)0.f;
        *(bf16x8*)&As[rr * 416 + cc] = z;
    }
    __syncthreads();

    int w = tid >> 6, lane = tid & 63, q = lane >> 4, r15 = lane & 15;
    f32x4 acc = {0.f, 0.f, 0.f, 0.f};
    const float* pB = Bw + (size_t)(w * 16 + r15) * 400;
#pragma unroll 4
    for (int kt = 0; kt < 13; ++kt) {
        int k0 = kt * 32 + q * 8;
        bf16x8 a = *(const bf16x8*)&As[r15 * 416 + k0];
        bf16x8 bb;
#pragma unroll
        for (int k = 0; k < 8; ++k) bb[k] = (bf16)0.f;
        if (k0 < 400) {
            f32x4 c0 = *(const f32x4*)(pB + k0);
            f32x4 c1 = *(const f32x4*)(pB + k0 + 4);
            bb[0] = (bf16)c0[0]; bb[1] = (bf16)c0[1]; bb[2] = (bf16)c0[2]; bb[3] = (bf16)c0[3];
            bb[4] = (bf16)c1[0]; bb[5] = (bf16)c1[1]; bb[6] = (bf16)c1[2]; bb[7] = (bf16)c1[3];
        }
        acc = __builtin_amdgcn_mfma_f32_16x16x32_bf16(a, bb, acc, 0, 0, 0);
    }
#pragma unroll
    for (int r = 0; r < 4; ++r) {
        int mm = m0 + q * 4 + r;
        int nn = w * 16 + r15;
        float v = fmaxf(acc[r] + bias[nn], 0.f);
        Cout[(size_t)mm * 64 + nn] = v;
    }
}

// ---------------- K8: BN2+relu+maxpool + concat + FC ----------------
__global__ __launch_bounds__(256) void k8_final(
    const bf16* __restrict__ g2out,       // [4096][64][32]
    const float* __restrict__ scale2, const float* __restrict__ shift2,
    const float* __restrict__ h2,         // [4096][64]
    const float* __restrict__ Wfc,        // [2][96]
    const float* __restrict__ bfc,
    float* __restrict__ out)              // [4096][2]
{
    __shared__ float s2s[64], sh2s[64];
    int tid = threadIdx.x;
    if (tid < 64) { s2s[tid] = scale2[tid]; sh2s[tid] = shift2[tid]; }
    __syncthreads();
    int w = tid >> 6, lane = tid & 63;
    int b = blockIdx.x * 4 + w;
    int c = lane & 31, half = lane >> 5;
    const bf16* gb = g2out + (size_t)b * 2048;
    float mx = 0.f;
    for (int i = 0; i < 32; ++i) {
        int n = half * 32 + i;
        float v = (float)gb[n * 32 + c];
        float val = fmaf(s2s[n], v, sh2s[n]);
        mx = fmaxf(mx, val);
    }
    mx = fmaxf(mx, __shfl_xor(mx, 32));
    float h2v = h2[(size_t)b * 64 + lane];
#pragma unroll
    for (int o = 0; o < 2; ++o) {
        float t = h2v * Wfc[o * 96 + 32 + lane];
        if (half == 0) t += mx * Wfc[o * 96 + c];
#pragma unroll
        for (int off = 32; off > 0; off >>= 1) t += __shfl_xor(t, off);
        if (lane == 0) out[(size_t)b * 2 + o] = t + bfc[o];
    }
}

extern "C" void kernel_launch(void* const* d_in, const int* in_sizes, int n_in,
                              void* d_out, int out_size, void* d_ws, size_t ws_size,
                              hipStream_t stream)
{
    const float* x_fp   = (const float*)d_in[0];
    const float* x_node = (const float*)d_in[1];
    const int*   edge   = (const int*)d_in[2];
    const float* W1     = (const float*)d_in[3];
    const float* b1     = (const float*)d_in[4];
    const float* g1     = (const float*)d_in[5];
    const float* be1    = (const float*)d_in[6];
    const float* W2     = (const float*)d_in[7];
    const float* b2     = (const float*)d_in[8];
    const float* g2     = (const float*)d_in[9];
    const float* be2    = (const float*)d_in[10];
    const float* Wl1    = (const float*)d_in[11];
    const float* bl1    = (const float*)d_in[12];
    const float* Wl2    = (const float*)d_in[13];
    const float* bl2    = (const float*)d_in[14];
    const float* Wfc    = (const float*)d_in[15];
    const float* bfc    = (const float*)d_in[16];
    float* out = (float*)d_out;

    char* ws = (char*)d_ws;
    float* ahat    = (float*)(ws);                    // 16384 B
    float* scale1  = (float*)(ws + 16384);
    float* shift1  = (float*)(ws + 16640);
    float* scale2  = (float*)(ws + 16896);
    float* shift2  = (float*)(ws + 17152);
    float* part1   = (float*)(ws + 20480);            // 65536 B
    float* part2   = (float*)(ws + 86016);            // 65536 B (contiguous with part1)
    bf16*  g1out   = (bf16*)(ws + 151552);            // 33554432 B (dead after k3 -> part6)
    float* part6   = (float*)(ws + 151552);           // 26214400 B overlay
    bf16*  g2out   = (bf16*)(ws + 33705984ull);       // 16777216 B
    bf16*  h1      = (bf16*)(ws + 50483200ull);       // 3276800 B
    float* h2      = (float*)(ws + 53760000ull);      // 1048576 B

    k0_prep<<<dim3(16), dim3(256), 0, stream>>>(edge, part1, ahat);
    k1_gcn1<<<dim3(4096), dim3(64), 0, stream>>>(x_node, W1, b1, ahat, g1out, part1);
    k_bnstats<<<dim3(64), dim3(64), 0, stream>>>(part1, g1, be1, scale1, shift1,
                                                 1.f / (4096.f * 64.f));
    k3_gcn2<<<dim3(4096), dim3(64), 0, stream>>>(g1out, W2, b2, scale1, shift1, ahat,
                                                 g2out, part2);
    k_bnstats<<<dim3(64), dim3(64), 0, stream>>>(part2, g2, be2, scale2, shift2,
                                                 1.f / (4096.f * 32.f));
    k6_mlp1<<<dim3(64, 7, 4), dim3(256), 0, stream>>>(x_fp, Wl1, part6);
    k6_reduce<<<dim3(1600), dim3(256), 0, stream>>>(part6, bl1, h1);
    k7_mlp2<<<dim3(256), dim3(256), 0, stream>>>(h1, Wl2, bl2, h2);
    k8_final<<<dim3(1024), dim3(256), 0, stream>>>(g2out, scale2, shift2, h2, Wfc, bfc, out);
}

// Round 4
// 285.917 us; speedup vs baseline: 1.5868x; 1.5868x over previous
//
#include <hip/hip_runtime.h>
#include <hip/hip_bf16.h>
#include <math.h>

typedef __bf16 bf16;
typedef __attribute__((ext_vector_type(8))) __bf16 bf16x8;
typedef __attribute__((ext_vector_type(4))) __bf16 bf16x4;
typedef __attribute__((ext_vector_type(4))) float f32x4;

#define EPSBN 1e-5f
#define NSLOT 128

// ---------------- K0: zero stat partials; build bf16 Ahat/W1/W2 in padded layouts ----------------
// Ahat[d][s] = sum over edges (s->d) of dinv[s]*dinv[d], incl. self loops. Duplicate edges add.
__global__ __launch_bounds__(256) void k0_prep(const int* __restrict__ edge,
    const float* __restrict__ W1, const float* __restrict__ W2,
    float* __restrict__ partials,          // 32768 floats (part1+part2)
    bf16* __restrict__ ahb,                // [64][72] bf16, cols 64..71 zero
    bf16* __restrict__ w1b,                // [64][104] bf16, cols 67..103 zero
    bf16* __restrict__ w2b)                // [32][72] bf16, cols 64..71 zero
{
    int tid = threadIdx.x;
    for (int i = blockIdx.x * 256 + tid; i < NSLOT * 64 * 4; i += gridDim.x * 256)
        partials[i] = 0.f;
    if (blockIdx.x == 1) {
        for (int i = tid; i < 64 * 104; i += 256) {
            int n = i / 104, f = i % 104;
            w1b[i] = (bf16)((f < 67) ? W1[n * 67 + f] : 0.f);
        }
        return;
    }
    if (blockIdx.x == 2) {
        for (int i = tid; i < 32 * 72; i += 256) {
            int n = i / 72, f = i % 72;
            w2b[i] = (bf16)((f < 64) ? W2[n * 64 + f] : 0.f);
        }
        return;
    }
    if (blockIdx.x != 0) return;

    __shared__ float Ah[64 * 64];
    __shared__ int deg[64];
    __shared__ float dinv[64];
    for (int i = tid; i < 4096; i += 256) Ah[i] = 0.f;
    if (tid < 64) deg[tid] = 1;                       // self loop
    __syncthreads();
    for (int e = tid; e < 512; e += 256) atomicAdd(&deg[edge[512 + e]], 1);
    __syncthreads();
    if (tid < 64) dinv[tid] = rsqrtf((float)deg[tid]);
    __syncthreads();
    for (int e = tid; e < 512; e += 256) {
        int s = edge[e], d = edge[512 + e];
        atomicAdd(&Ah[d * 64 + s], dinv[s] * dinv[d]);
    }
    if (tid < 64) atomicAdd(&Ah[tid * 64 + tid], dinv[tid] * dinv[tid]);
    __syncthreads();
    for (int i = tid; i < 64 * 72; i += 256) {
        int n = i / 72, s = i % 72;
        ahb[i] = (bf16)((s < 64) ? Ah[n * 64 + s] : 0.f);
    }
}

// ---------------- K1: GCN layer 1 — 4 samples/block (wave w -> sample), all-MFMA ----------------
// MFMA1: hT[o][n] = sum_f W1[o][f] X[n][f];  MFMA2: out[n][c] = sum_s Ahat[n][s] hT[c][s]
__global__ __launch_bounds__(256) void k1_gcn1(
    const float* __restrict__ x,          // [B][64][67]
    const bf16* __restrict__ w1b,         // [64][104]
    const bf16* __restrict__ ahb,         // [64][72]
    const float* __restrict__ b1,         // [64]
    bf16* __restrict__ g1out,             // [B][64][64]
    float* __restrict__ part1)            // [NSLOT][64][2]
{
    __shared__ bf16 sW[64 * 104];         // 13312 B
    __shared__ bf16 sX[4 * 64 * 104];     // 53248 B; per-sample 6656 bf16; overlays hT then out
    __shared__ bf16 sAh[64 * 72];         // 9216 B
    __shared__ float sstat[128];
    int tid = threadIdx.x;
    int blk = blockIdx.x;
    if (tid < 128) sstat[tid] = 0.f;

    // stage W1 (832 chunks) and Ahat (576 chunks) via 16B copies
#pragma unroll
    for (int k = 0; k < 4; ++k) {
        int c = tid + (k << 8);
        if (c < 832) ((bf16x8*)sW)[c] = ((const bf16x8*)w1b)[c];
    }
#pragma unroll
    for (int k = 0; k < 3; ++k) {
        int c = tid + (k << 8);
        if (c < 576) ((bf16x8*)sAh)[c] = ((const bf16x8*)ahb)[c];
    }
    // stage X: 4 samples = 17152 floats, coalesced dword loads
    const float* xb = x + (size_t)blk * 17152;
    for (int k = 0; k < 67; ++k) {
        int j = tid + (k << 8);
        int s = j / 4288, r = j % 4288;
        int n = r / 67, f = r % 67;
        sX[s * 6656 + n * 104 + f] = (bf16)xb[j];
    }
    // zero pad f in [67,96)
    for (int k = 0; k < 29; ++k) {
        int j = tid + (k << 8);
        int s = j / 1856, r = j % 1856;
        int n = r / 29, f = 67 + r % 29;
        sX[s * 6656 + n * 104 + f] = (bf16)0.f;
    }
    __syncthreads();

    int w = tid >> 6, lane = tid & 63, q = lane >> 4, r15 = lane & 15;
    bf16* myX = sX + w * 6656;
    f32x4 z4 = {0.f, 0.f, 0.f, 0.f};
    f32x4 acc[4][4];
#pragma unroll
    for (int mt = 0; mt < 4; ++mt)
#pragma unroll
        for (int nt = 0; nt < 4; ++nt) acc[mt][nt] = z4;
#pragma unroll
    for (int kt = 0; kt < 3; ++kt) {
        bf16x8 a_[4], b_[4];
#pragma unroll
        for (int mt = 0; mt < 4; ++mt)
            a_[mt] = *(const bf16x8*)&sW[(mt * 16 + r15) * 104 + kt * 32 + q * 8];
#pragma unroll
        for (int nt = 0; nt < 4; ++nt)
            b_[nt] = *(const bf16x8*)&myX[(nt * 16 + r15) * 104 + kt * 32 + q * 8];
#pragma unroll
        for (int mt = 0; mt < 4; ++mt)
#pragma unroll
            for (int nt = 0; nt < 4; ++nt)
                acc[mt][nt] = __builtin_amdgcn_mfma_f32_16x16x32_bf16(a_[mt], b_[nt], acc[mt][nt], 0, 0, 0);
    }
    // write hT[o][n] over my X region (pitch 104); same-wave DS ordering keeps this safe
#pragma unroll
    for (int mt = 0; mt < 4; ++mt)
#pragma unroll
        for (int nt = 0; nt < 4; ++nt)
#pragma unroll
            for (int r = 0; r < 4; ++r)
                myX[(mt * 16 + q * 4 + r) * 104 + nt * 16 + r15] = (bf16)acc[mt][nt][r];

    bf16x8 ah[4][2], hb[4][2];
#pragma unroll
    for (int mt = 0; mt < 4; ++mt)
#pragma unroll
        for (int kt = 0; kt < 2; ++kt)
            ah[mt][kt] = *(const bf16x8*)&sAh[(mt * 16 + r15) * 72 + kt * 32 + q * 8];
#pragma unroll
    for (int ct = 0; ct < 4; ++ct)
#pragma unroll
        for (int kt = 0; kt < 2; ++kt)
            hb[ct][kt] = *(const bf16x8*)&myX[(ct * 16 + r15) * 104 + kt * 32 + q * 8];

    f32x4 o2[4][4];
#pragma unroll
    for (int mt = 0; mt < 4; ++mt)
#pragma unroll
        for (int ct = 0; ct < 4; ++ct) o2[mt][ct] = z4;
#pragma unroll
    for (int kt = 0; kt < 2; ++kt)
#pragma unroll
        for (int mt = 0; mt < 4; ++mt)
#pragma unroll
            for (int ct = 0; ct < 4; ++ct)
                o2[mt][ct] = __builtin_amdgcn_mfma_f32_16x16x32_bf16(ah[mt][kt], hb[ct][kt], o2[mt][ct], 0, 0, 0);

    float bv[4];
#pragma unroll
    for (int ct = 0; ct < 4; ++ct) bv[ct] = b1[ct * 16 + r15];
    // out staging over my region, pitch 72 (hb fully loaded -> safe to overwrite hT)
#pragma unroll
    for (int mt = 0; mt < 4; ++mt)
#pragma unroll
        for (int ct = 0; ct < 4; ++ct)
#pragma unroll
            for (int r = 0; r < 4; ++r)
                myX[(mt * 16 + q * 4 + r) * 72 + ct * 16 + r15] = (bf16)(o2[mt][ct][r] + bv[ct]);
    __syncthreads();

    // cooperative coalesced store + stats: 2048 16B-chunks, global offset = chunk*8 elems
    bf16* gp = g1out + (size_t)blk * 16384;
#pragma unroll
    for (int k = 0; k < 8; ++k) {
        int c = tid + (k << 8);
        int s = c >> 9, rc = c & 511, n = rc >> 3, cc = rc & 7;
        bf16x8 v = *(const bf16x8*)&sX[s * 6656 + n * 72 + cc * 8];
        ((bf16x8*)gp)[c] = v;
        float s1 = 0.f, s2 = 0.f;
#pragma unroll
        for (int j = 0; j < 8; ++j) { float f = (float)v[j]; s1 += f; s2 += f * f; }
        atomicAdd(&sstat[n * 2 + 0], s1);
        atomicAdd(&sstat[n * 2 + 1], s2);
    }
    __syncthreads();
    if (tid < 64) {
        int slot = blk & (NSLOT - 1);
        atomicAdd(&part1[(slot * 64 + tid) * 2 + 0], sstat[tid * 2 + 0]);
        atomicAdd(&part1[(slot * 64 + tid) * 2 + 1], sstat[tid * 2 + 1]);
    }
}

// ---------------- BN stats reduce: partials -> scale/shift per node ----------------
__global__ __launch_bounds__(64) void k_bnstats(
    const float* __restrict__ part,       // [NSLOT][64][2]
    const float* __restrict__ gamma, const float* __restrict__ beta,
    float* __restrict__ scale, float* __restrict__ shift, float inv_count)
{
    int n = blockIdx.x, t = threadIdx.x;
    float s1 = part[(t * 64 + n) * 2] + part[((t + 64) * 64 + n) * 2];
    float s2 = part[(t * 64 + n) * 2 + 1] + part[((t + 64) * 64 + n) * 2 + 1];
#pragma unroll
    for (int o = 32; o > 0; o >>= 1) { s1 += __shfl_down(s1, o); s2 += __shfl_down(s2, o); }
    if (t == 0) {
        float mean = s1 * inv_count;
        float var = s2 * inv_count - mean * mean;
        float sc = gamma[n] * rsqrtf(var + EPSBN);
        scale[n] = sc;
        shift[n] = beta[n] - mean * sc;
    }
}

// ---------------- K3: BN1+relu -> GCN layer 2 — 4 samples/block, all-MFMA ----------------
__global__ __launch_bounds__(256) void k3_gcn2(
    const bf16* __restrict__ g1out,       // [B][64][64]
    const bf16* __restrict__ w2b,         // [32][72]
    const bf16* __restrict__ ahb,         // [64][72]
    const float* __restrict__ b2,
    const float* __restrict__ scale1, const float* __restrict__ shift1,
    bf16* __restrict__ g2out,             // [B][64][32]
    float* __restrict__ part2)
{
    __shared__ bf16 sW[32 * 72];          // 4608 B
    __shared__ bf16 sY[4 * 64 * 72];      // 36864 B; per-sample 4608 bf16; overlays hT then out
    __shared__ bf16 sAh[64 * 72];         // 9216 B
    __shared__ float sstat[128];
    __shared__ float ssc[64], ssh[64];
    int tid = threadIdx.x;
    int blk = blockIdx.x;
    if (tid < 128) sstat[tid] = 0.f;
    if (tid < 64) { ssc[tid] = scale1[tid]; ssh[tid] = shift1[tid]; }
#pragma unroll
    for (int k = 0; k < 2; ++k) {
        int c = tid + (k << 8);
        if (c < 288) ((bf16x8*)sW)[c] = ((const bf16x8*)w2b)[c];
    }
#pragma unroll
    for (int k = 0; k < 3; ++k) {
        int c = tid + (k << 8);
        if (c < 576) ((bf16x8*)sAh)[c] = ((const bf16x8*)ahb)[c];
    }
    __syncthreads();                      // ssc/ssh ready for Y staging

    // stage Y = relu(scale*g1+shift) : 2048 coalesced 16B chunks
    const bf16* gb = g1out + (size_t)blk * 16384;
#pragma unroll
    for (int k = 0; k < 8; ++k) {
        int c = tid + (k << 8);
        int s = c >> 9, rc = c & 511, n = rc >> 3, cc = rc & 7;
        bf16x8 g = ((const bf16x8*)gb)[c];
        float sc = ssc[n], sh = ssh[n];
        bf16x8 y;
#pragma unroll
        for (int j = 0; j < 8; ++j)
            y[j] = (bf16)fmaxf(fmaf(sc, (float)g[j], sh), 0.f);
        *(bf16x8*)&sY[s * 4608 + n * 72 + cc * 8] = y;
    }
    __syncthreads();

    int w = tid >> 6, lane = tid & 63, q = lane >> 4, r15 = lane & 15;
    bf16* myY = sY + w * 4608;
    f32x4 z4 = {0.f, 0.f, 0.f, 0.f};
    f32x4 acc[2][4];
#pragma unroll
    for (int mt = 0; mt < 2; ++mt)
#pragma unroll
        for (int nt = 0; nt < 4; ++nt) acc[mt][nt] = z4;
#pragma unroll
    for (int kt = 0; kt < 2; ++kt) {
        bf16x8 a_[2], b_[4];
#pragma unroll
        for (int mt = 0; mt < 2; ++mt)
            a_[mt] = *(const bf16x8*)&sW[(mt * 16 + r15) * 72 + kt * 32 + q * 8];
#pragma unroll
        for (int nt = 0; nt < 4; ++nt)
            b_[nt] = *(const bf16x8*)&myY[(nt * 16 + r15) * 72 + kt * 32 + q * 8];
#pragma unroll
        for (int mt = 0; mt < 2; ++mt)
#pragma unroll
            for (int nt = 0; nt < 4; ++nt)
                acc[mt][nt] = __builtin_amdgcn_mfma_f32_16x16x32_bf16(a_[mt], b_[nt], acc[mt][nt], 0, 0, 0);
    }
    // hT[o<32][n] over my Y region, pitch 72
#pragma unroll
    for (int mt = 0; mt < 2; ++mt)
#pragma unroll
        for (int nt = 0; nt < 4; ++nt)
#pragma unroll
            for (int r = 0; r < 4; ++r)
                myY[(mt * 16 + q * 4 + r) * 72 + nt * 16 + r15] = (bf16)acc[mt][nt][r];

    bf16x8 ah[4][2], hb[2][2];
#pragma unroll
    for (int mt = 0; mt < 4; ++mt)
#pragma unroll
        for (int kt = 0; kt < 2; ++kt)
            ah[mt][kt] = *(const bf16x8*)&sAh[(mt * 16 + r15) * 72 + kt * 32 + q * 8];
#pragma unroll
    for (int ct = 0; ct < 2; ++ct)
#pragma unroll
        for (int kt = 0; kt < 2; ++kt)
            hb[ct][kt] = *(const bf16x8*)&myY[(ct * 16 + r15) * 72 + kt * 32 + q * 8];

    f32x4 o2[4][2];
#pragma unroll
    for (int mt = 0; mt < 4; ++mt)
#pragma unroll
        for (int ct = 0; ct < 2; ++ct) o2[mt][ct] = z4;
#pragma unroll
    for (int kt = 0; kt < 2; ++kt)
#pragma unroll
        for (int mt = 0; mt < 4; ++mt)
#pragma unroll
            for (int ct = 0; ct < 2; ++ct)
                o2[mt][ct] = __builtin_amdgcn_mfma_f32_16x16x32_bf16(ah[mt][kt], hb[ct][kt], o2[mt][ct], 0, 0, 0);

    float bv[2];
#pragma unroll
    for (int ct = 0; ct < 2; ++ct) bv[ct] = b2[ct * 16 + r15];
    // out staging pitch 40 (16B-aligned rows), overwrites hT (hb loaded)
#pragma unroll
    for (int mt = 0; mt < 4; ++mt)
#pragma unroll
        for (int ct = 0; ct < 2; ++ct)
#pragma unroll
            for (int r = 0; r < 4; ++r)
                myY[(mt * 16 + q * 4 + r) * 40 + ct * 16 + r15] = (bf16)(o2[mt][ct][r] + bv[ct]);
    __syncthreads();

    // store + stats: 1024 chunks, global offset = chunk*8
    bf16* gp = g2out + (size_t)blk * 8192;
#pragma unroll
    for (int k = 0; k < 4; ++k) {
        int c = tid + (k << 8);
        int s = c >> 8, rc = c & 255, n = rc >> 2, cc = rc & 3;
        bf16x8 v = *(const bf16x8*)&sY[s * 4608 + n * 40 + cc * 8];
        ((bf16x8*)gp)[c] = v;
        float s1 = 0.f, s2 = 0.f;
#pragma unroll
        for (int j = 0; j < 8; ++j) { float f = (float)v[j]; s1 += f; s2 += f * f; }
        atomicAdd(&sstat[n * 2 + 0], s1);
        atomicAdd(&sstat[n * 2 + 1], s2);
    }
    __syncthreads();
    if (tid < 64) {
        int slot = blk & (NSLOT - 1);
        atomicAdd(&part2[(slot * 64 + tid) * 2 + 0], sstat[tid * 2 + 0]);
        atomicAdd(&part2[(slot * 64 + tid) * 2 + 1], sstat[tid * 2 + 1]);
    }
}

// ---------------- K6: MLP1 split-K GEMM, register-prefetch pipeline ----------------
__global__ __launch_bounds__(256) void k6_mlp1(
    const float* __restrict__ A,          // [4096][2048]
    const float* __restrict__ Bw,         // [400][2048]
    float* __restrict__ part)             // [4][4096][400]
{
    __shared__ bf16 As[64 * 36];
    __shared__ bf16 Bs[64 * 36];
    int tid = threadIdx.x;
    int m0 = blockIdx.x * 64, n0 = blockIdx.y * 64, ks = blockIdx.z;
    int row = tid >> 2, seg = tid & 3;
    int w = tid >> 6, lane = tid & 63, q = lane >> 4, r15 = lane & 15;
    f32x4 z4 = {0.f, 0.f, 0.f, 0.f};
    f32x4 acc[4] = {z4, z4, z4, z4};
    const float* pA = A + (size_t)(m0 + row) * 2048 + ks * 512 + seg * 8;
    bool bvalid = (n0 + row) < 400;
    const float* pB = Bw + (size_t)(n0 + row) * 2048 + ks * 512 + seg * 8;

    f32x4 a0 = *(const f32x4*)pA;
    f32x4 a1 = *(const f32x4*)(pA + 4);
    f32x4 c0 = z4, c1 = z4;
    if (bvalid) { c0 = *(const f32x4*)pB; c1 = *(const f32x4*)(pB + 4); }

    for (int kt = 0; kt < 16; ++kt) {
        bf16x8 apk, bpk;
        apk[0] = (bf16)a0[0]; apk[1] = (bf16)a0[1]; apk[2] = (bf16)a0[2]; apk[3] = (bf16)a0[3];
        apk[4] = (bf16)a1[0]; apk[5] = (bf16)a1[1]; apk[6] = (bf16)a1[2]; apk[7] = (bf16)a1[3];
        bpk[0] = (bf16)c0[0]; bpk[1] = (bf16)c0[1]; bpk[2] = (bf16)c0[2]; bpk[3] = (bf16)c0[3];
        bpk[4] = (bf16)c1[0]; bpk[5] = (bf16)c1[1]; bpk[6] = (bf16)c1[2]; bpk[7] = (bf16)c1[3];
        __syncthreads();
        *(bf16x8*)&As[row * 36 + seg * 8] = apk;
        *(bf16x8*)&Bs[row * 36 + seg * 8] = bpk;
        __syncthreads();
        if (kt < 15) {
            pA += 32; pB += 32;
            a0 = *(const f32x4*)pA; a1 = *(const f32x4*)(pA + 4);
            if (bvalid) { c0 = *(const f32x4*)pB; c1 = *(const f32x4*)(pB + 4); }
        }
        bf16x8 a = *(const bf16x8*)&As[(w * 16 + r15) * 36 + q * 8];
#pragma unroll
        for (int nt = 0; nt < 4; ++nt) {
            bf16x8 bb = *(const bf16x8*)&Bs[(nt * 16 + r15) * 36 + q * 8];
            acc[nt] = __builtin_amdgcn_mfma_f32_16x16x32_bf16(a, bb, acc[nt], 0, 0, 0);
        }
    }
    float* pp = part + (size_t)ks * 1638400;
#pragma unroll
    for (int nt = 0; nt < 4; ++nt)
#pragma unroll
        for (int r = 0; r < 4; ++r) {
            int mm = m0 + w * 16 + q * 4 + r;
            int nn = n0 + nt * 16 + r15;
            if (nn < 400) pp[(size_t)mm * 400 + nn] = acc[nt][r];
        }
}

// ---------------- K6R: reduce 4 k-splits + bias + relu -> bf16 h1 ----------------
__global__ __launch_bounds__(256) void k6_reduce(
    const float* __restrict__ part,
    const float* __restrict__ bias,
    bf16* __restrict__ h1)
{
    int i = blockIdx.x * 256 + threadIdx.x;
    const f32x4* p = (const f32x4*)part;
    f32x4 s0 = p[i], s1v = p[i + 409600], s2v = p[i + 819200], s3v = p[i + 1228800];
    int nn = (i * 4) % 400;
    f32x4 bv = *(const f32x4*)&bias[nn];
    bf16x4 ov;
    ov[0] = (bf16)fmaxf(s0[0] + s1v[0] + s2v[0] + s3v[0] + bv[0], 0.f);
    ov[1] = (bf16)fmaxf(s0[1] + s1v[1] + s2v[1] + s3v[1] + bv[1], 0.f);
    ov[2] = (bf16)fmaxf(s0[2] + s1v[2] + s2v[2] + s3v[2] + bv[2], 0.f);
    ov[3] = (bf16)fmaxf(s0[3] + s1v[3] + s2v[3] + s3v[3] + bv[3], 0.f);
    *(bf16x4*)&h1[i * 4] = ov;
}

// ---------------- K7: MLP2  h2 = relu(h1 @ Wl2^T + bl2) ----------------
__global__ __launch_bounds__(256) void k7_mlp2(
    const bf16* __restrict__ A,           // [4096][400] bf16
    const float* __restrict__ Bw,         // [64][400] f32
    const float* __restrict__ bias,
    float* __restrict__ Cout)             // [4096][64]
{
    __shared__ bf16 As[16 * 416];
    int tid = threadIdx.x;
    int m0 = blockIdx.x * 16;
    for (int i = tid; i < 16 * 50; i += 256) {
        int rr = i / 50, cc = (i % 50) * 8;
        *(bf16x8*)&As[rr * 416 + cc] = *(const bf16x8*)(A + (size_t)(m0 + rr) * 400 + cc);
    }
    if (tid < 32) {
        int rr = tid >> 1, cc = 400 + (tid & 1) * 8;
        bf16x8 z;
#pragma unroll
        for (int k = 0; k < 8; ++k) z[k] = (bf16)0.f;
        *(bf16x8*)&As[rr * 416 + cc] = z;
    }
    __syncthreads();

    int w = tid >> 6, lane = tid & 63, q = lane >> 4, r15 = lane & 15;
    f32x4 acc = {0.f, 0.f, 0.f, 0.f};
    const float* pB = Bw + (size_t)(w * 16 + r15) * 400;
#pragma unroll 4
    for (int kt = 0; kt < 13; ++kt) {
        int k0 = kt * 32 + q * 8;
        bf16x8 a = *(const bf16x8*)&As[r15 * 416 + k0];
        bf16x8 bb;
#pragma unroll
        for (int k = 0; k < 8; ++k) bb[k] = (bf16)0.f;
        if (k0 < 400) {
            f32x4 c0 = *(const f32x4*)(pB + k0);
            f32x4 c1 = *(const f32x4*)(pB + k0 + 4);
            bb[0] = (bf16)c0[0]; bb[1] = (bf16)c0[1]; bb[2] = (bf16)c0[2]; bb[3] = (bf16)c0[3];
            bb[4] = (bf16)c1[0]; bb[5] = (bf16)c1[1]; bb[6] = (bf16)c1[2]; bb[7] = (bf16)c1[3];
        }
        acc = __builtin_amdgcn_mfma_f32_16x16x32_bf16(a, bb, acc, 0, 0, 0);
    }
#pragma unroll
    for (int r = 0; r < 4; ++r) {
        int mm = m0 + q * 4 + r;
        int nn = w * 16 + r15;
        float v = fmaxf(acc[r] + bias[nn], 0.f);
        Cout[(size_t)mm * 64 + nn] = v;
    }
}

// ---------------- K8: BN2+relu+maxpool + concat + FC ----------------
__global__ __launch_bounds__(256) void k8_final(
    const bf16* __restrict__ g2out,       // [4096][64][32]
    const float* __restrict__ scale2, const float* __restrict__ shift2,
    const float* __restrict__ h2,         // [4096][64]
    const float* __restrict__ Wfc,        // [2][96]
    const float* __restrict__ bfc,
    float* __restrict__ out)              // [4096][2]
{
    __shared__ float s2s[64], sh2s[64];
    int tid = threadIdx.x;
    if (tid < 64) { s2s[tid] = scale2[tid]; sh2s[tid] = shift2[tid]; }
    __syncthreads();
    int w = tid >> 6, lane = tid & 63;
    int b = blockIdx.x * 4 + w;
    int c = lane & 31, half = lane >> 5;
    const bf16* gb = g2out + (size_t)b * 2048;
    float mx = 0.f;
    for (int i = 0; i < 32; ++i) {
        int n = half * 32 + i;
        float v = (float)gb[n * 32 + c];
        float val = fmaf(s2s[n], v, sh2s[n]);
        mx = fmaxf(mx, val);
    }
    mx = fmaxf(mx, __shfl_xor(mx, 32));
    float h2v = h2[(size_t)b * 64 + lane];
#pragma unroll
    for (int o = 0; o < 2; ++o) {
        float t = h2v * Wfc[o * 96 + 32 + lane];
        if (half == 0) t += mx * Wfc[o * 96 + c];
#pragma unroll
        for (int off = 32; off > 0; off >>= 1) t += __shfl_xor(t, off);
        if (lane == 0) out[(size_t)b * 2 + o] = t + bfc[o];
    }
}

extern "C" void kernel_launch(void* const* d_in, const int* in_sizes, int n_in,
                              void* d_out, int out_size, void* d_ws, size_t ws_size,
                              hipStream_t stream)
{
    const float* x_fp   = (const float*)d_in[0];
    const float* x_node = (const float*)d_in[1];
    const int*   edge   = (const int*)d_in[2];
    const float* W1     = (const float*)d_in[3];
    const float* b1     = (const float*)d_in[4];
    const float* g1     = (const float*)d_in[5];
    const float* be1    = (const float*)d_in[6];
    const float* W2     = (const float*)d_in[7];
    const float* b2     = (const float*)d_in[8];
    const float* g2     = (const float*)d_in[9];
    const float* be2    = (const float*)d_in[10];
    const float* Wl1    = (const float*)d_in[11];
    const float* bl1    = (const float*)d_in[12];
    const float* Wl2    = (const float*)d_in[13];
    const float* bl2    = (const float*)d_in[14];
    const float* Wfc    = (const float*)d_in[15];
    const float* bfc    = (const float*)d_in[16];
    float* out = (float*)d_out;

    char* ws = (char*)d_ws;
    bf16*  w1b     = (bf16*)(ws);                     // 13312 B
    bf16*  ahb     = (bf16*)(ws + 13312);             // 9216 B
    bf16*  w2b     = (bf16*)(ws + 22528);             // 4608 B
    float* scale1  = (float*)(ws + 27136);
    float* shift1  = (float*)(ws + 27392);
    float* scale2  = (float*)(ws + 27648);
    float* shift2  = (float*)(ws + 27904);
    float* part1   = (float*)(ws + 28672);            // 65536 B
    float* part2   = (float*)(ws + 94208);            // 65536 B (contiguous with part1)
    bf16*  g1out   = (bf16*)(ws + 159744);            // 33554432 B (dead after k3 -> part6)
    float* part6   = (float*)(ws + 159744);           // 26214400 B overlay
    bf16*  g2out   = (bf16*)(ws + 33714176ull);       // 16777216 B
    bf16*  h1      = (bf16*)(ws + 50491392ull);       // 3276800 B
    float* h2      = (float*)(ws + 53768192ull);      // 1048576 B

    k0_prep<<<dim3(16), dim3(256), 0, stream>>>(edge, W1, W2, part1, ahb, w1b, w2b);
    k1_gcn1<<<dim3(1024), dim3(256), 0, stream>>>(x_node, w1b, ahb, b1, g1out, part1);
    k_bnstats<<<dim3(64), dim3(64), 0, stream>>>(part1, g1, be1, scale1, shift1,
                                                 1.f / (4096.f * 64.f));
    k3_gcn2<<<dim3(1024), dim3(256), 0, stream>>>(g1out, w2b, ahb, b2, scale1, shift1,
                                                  g2out, part2);
    k_bnstats<<<dim3(64), dim3(64), 0, stream>>>(part2, g2, be2, scale2, shift2,
                                                 1.f / (4096.f * 32.f));
    k6_mlp1<<<dim3(64, 7, 4), dim3(256), 0, stream>>>(x_fp, Wl1, part6);
    k6_reduce<<<dim3(1600), dim3(256), 0, stream>>>(part6, bl1, h1);
    k7_mlp2<<<dim3(256), dim3(256), 0, stream>>>(h1, Wl2, bl2, h2);
    k8_final<<<dim3(1024), dim3(256), 0, stream>>>(g2out, scale2, shift2, h2, Wfc, bfc, out);
}